// Round 9
// baseline (1004.806 us; speedup 1.0000x reference)
//
#include <hip/hip_runtime.h>
#include <stdint.h>

typedef unsigned short u16;
typedef float f32x4 __attribute__((ext_vector_type(4)));
typedef short s16x8 __attribute__((ext_vector_type(8)));
typedef short s16x4 __attribute__((ext_vector_type(4)));

constexpr int B  = 8;
constexpr int S  = 1024;
constexpr int DM = 1024;
constexpr int H  = 16;
constexpr int M  = B * S;          // 8192 rows
constexpr float NEGINF = -1e9f;

__device__ __forceinline__ u16 f2bf(float f) {
    union { float f; uint32_t u; } v; v.f = f;
    uint32_t u = v.u;
    uint32_t r = 0x7FFFu + ((u >> 16) & 1u);   // round-to-nearest-even
    return (u16)((u + r) >> 16);
}
__device__ __forceinline__ float bf2f(u16 h) {
    union { uint32_t u; float f; } v; v.u = ((uint32_t)h) << 16; return v.f;
}

// async global->LDS 16B (m97 form): LDS dest = wave-uniform base + lane*16
__device__ __forceinline__ void gload16(const u16* g, u16* l) {
    __builtin_amdgcn_global_load_lds(
        (const __attribute__((address_space(1))) unsigned int*)g,
        (__attribute__((address_space(3))) unsigned int*)l, 16, 0, 0);
}

// ---------------- fp32 -> bf16, all three inputs in one launch ----------------
__global__ void cvt_all(const float* __restrict__ q, const float* __restrict__ k,
                        const float* __restrict__ v,
                        u16* __restrict__ xq, u16* __restrict__ xk, u16* __restrict__ xv) {
    const float* in; u16* out;
    if (blockIdx.y == 0)      { in = q; out = xq; }
    else if (blockIdx.y == 1) { in = k; out = xk; }
    else                      { in = v; out = xv; }
    int i = (blockIdx.x * 256 + threadIdx.x) * 4;
    float4 val = *(const float4*)(in + i);
    ushort4 o;
    o.x = f2bf(val.x); o.y = f2bf(val.y); o.z = f2bf(val.z); o.w = f2bf(val.w);
    *(ushort4*)(out + i) = o;
}

// ---------------- W[k][n] fp32 -> Wt[n][k] bf16, all four weights ----------------
__global__ void transpose_all(const float* __restrict__ w0, const float* __restrict__ w1,
                              const float* __restrict__ w2, const float* __restrict__ w3,
                              u16* __restrict__ o0, u16* __restrict__ o1,
                              u16* __restrict__ o2, u16* __restrict__ o3) {
    const float* W; u16* Wt;
    switch (blockIdx.z) {
        case 0:  W = w0; Wt = o0; break;
        case 1:  W = w1; Wt = o1; break;
        case 2:  W = w2; Wt = o2; break;
        default: W = w3; Wt = o3; break;
    }
    __shared__ float tile[32][33];
    int n0 = blockIdx.x * 32, k0 = blockIdx.y * 32;
    int tx = threadIdx.x & 31, ty = threadIdx.x >> 5;   // 32 x 8
#pragma unroll
    for (int r = 0; r < 4; ++r)
        tile[ty + r*8][tx] = W[(size_t)(k0 + ty + r*8) * DM + n0 + tx];
    __syncthreads();
#pragma unroll
    for (int r = 0; r < 4; ++r)
        Wt[(size_t)(n0 + ty + r*8) * DM + k0 + tx] = f2bf(tile[tx][ty + r*8]);
}

// ---------------- GEMM: C[M x 1024] = A[M x 1024] * Bt[1024 x 1024]^T ----------------
// m97 structure: 128x128 tile, BK=32, global_load_lds width=16, linear LDS.
// Grid (m,n) = (x,y): same-m blocks share the A-band and the same id%8 -> same XCD.
// EPI 0: C bf16 row-major.  EPI 1: V transposed -> Vt[(b*16+h)*64+d][s].  EPI 2: fp32 + resid.
template<int EPI>
__global__ __launch_bounds__(256, 2)
void gemm_bt(const u16* __restrict__ A, const u16* __restrict__ Bt,
             void* __restrict__ Cv, const float* __restrict__ resid)
{
    __shared__ u16 As[128 * 32];
    __shared__ u16 Bs[128 * 32];
    const int m0 = blockIdx.x * 128;
    const int n0 = blockIdx.y * 128;
    const int t = threadIdx.x;
    const int lane = t & 63;
    const int wid = t >> 6;
    const int wm = (wid >> 1) * 64;
    const int wn = (wid & 1) * 64;
    const int lr = lane & 15;
    const int lg = lane >> 4;

    const u16* Ag = A  + (size_t)(m0 + (t >> 2)) * 1024 + (t & 3) * 8;
    const u16* Bg = Bt + (size_t)(n0 + (t >> 2)) * 1024 + (t & 3) * 8;
    u16* Al = As + t * 8;
    u16* Bl = Bs + t * 8;

    f32x4 acc[4][4] = {};

    for (int kt = 0; kt < 32; ++kt) {
        const int ko = kt * 32;
        __syncthreads();
        gload16(Ag + ko,            Al);
        gload16(Ag + 64*1024 + ko,  Al + 64*32);
        gload16(Bg + ko,            Bl);
        gload16(Bg + 64*1024 + ko,  Bl + 64*32);
        __syncthreads();
        s16x8 af[4], bfr[4];
#pragma unroll
        for (int m = 0; m < 4; ++m)
            af[m] = *(const s16x8*)(As + (wm + m*16 + lr) * 32 + lg * 8);
#pragma unroll
        for (int n = 0; n < 4; ++n)
            bfr[n] = *(const s16x8*)(Bs + (wn + n*16 + lr) * 32 + lg * 8);
#pragma unroll
        for (int m = 0; m < 4; ++m)
#pragma unroll
            for (int n = 0; n < 4; ++n)
                acc[m][n] = __builtin_amdgcn_mfma_f32_16x16x32_bf16(af[m], bfr[n], acc[m][n], 0, 0, 0);
    }

#pragma unroll
    for (int m = 0; m < 4; ++m) {
#pragma unroll
        for (int n = 0; n < 4; ++n) {
            const int rg0 = m0 + wm + m*16 + lg*4;   // D row = (lane>>4)*4 + reg
            const int cg  = n0 + wn + n*16 + lr;     // D col = lane&15
            if constexpr (EPI == 0) {
                u16* C = (u16*)Cv;
#pragma unroll
                for (int r = 0; r < 4; ++r)
                    C[(size_t)(rg0 + r) * 1024 + cg] = f2bf(acc[m][n][r]);
            } else if constexpr (EPI == 1) {
                u16* C = (u16*)Cv;
                const int bb = rg0 >> 10;
                const int s0 = rg0 & 1023;
                const int hh = cg >> 6;
                const int dd = cg & 63;
                ushort4 pk;
                pk.x = f2bf(acc[m][n][0]); pk.y = f2bf(acc[m][n][1]);
                pk.z = f2bf(acc[m][n][2]); pk.w = f2bf(acc[m][n][3]);
                *(ushort4*)(C + (size_t)((bb*16 + hh)*64 + dd) * 1024 + s0) = pk;
            } else {
                float* C = (float*)Cv;
#pragma unroll
                for (int r = 0; r < 4; ++r) {
                    size_t idx = (size_t)(rg0 + r) * 1024 + cg;
                    C[idx] = acc[m][n][r] + resid[idx];
                }
            }
        }
    }
}

// ---------------- fused scores + softmax + attn-write + PV (LDS-staged K/V) ----------------
// Grid: 8192 1-D, XCD-swizzled (i bits [12:9]=gHi, [8:3]=qt, [2:0]=gLo; g=b*16+h).
// Block = 16 q-rows; k-loop = 16 chunks of 64 k, shared by all 4 waves.
// Per chunk: K [64k][64d] and V [64d][64k] staged via 16x gload16 into
// double-buffered LDS, XOR-swizzled (f(row)=(row&7)<<4) with pre-swizzled
// GLOBAL source (linear DMA dest) and swizzled ds_read addr (rule #21).
// Wave w consumes k-rows [w*16, w*16+16) of each chunk. Swapped QK^T (A=K,B=Q):
// lane holds q=lr, k=c*64+w*16+lg*4+r. P kept as bf16 raw-exp (paf[16], 32 VGPR).
// PV via 16x16x16 MFMA; invr[r] (rows q=lg*4+r) applied at the end.
// ctxp aliases the dead staging buffer (LDS total ~33 KB -> 4 blocks/CU).
__global__ __launch_bounds__(256, 2)
void attn_fused(const u16* __restrict__ Qp, const u16* __restrict__ Kp,
                const void* __restrict__ maskp, const u16* __restrict__ Vt,
                float* __restrict__ attn, u16* __restrict__ ctx)
{
    const int i  = blockIdx.x;
    const int qt = (i >> 3) & 63;
    const int g  = ((i >> 9) << 3) | (i & 7);   // g%8 == i%8 -> same XCD per (b,h)
    const int h  = g & 15;
    const int b  = g >> 4;
    const int q0 = qt * 16;

    const int t = threadIdx.x;
    const int lane = t & 63;
    const int w = t >> 6;
    const int lr = lane & 15;
    const int lg = lane >> 4;

    __shared__ u16 kvbuf[2][2][4096];   // [buf][0=K,1=V][64*64], 32 KB
    __shared__ float redB[4][16];

    // mask dtype detect
    uint32_t orv = 0;
    const uint32_t* mw = (const uint32_t*)maskp;
#pragma unroll
    for (int ii = 0; ii < 64; ++ii) orv |= mw[ii];
    const bool mask_bytes = (orv > 1u);

    // Q as B-operand: q = q0+lr, k-elem = d
    const u16* qb = Qp + (size_t)(b*S + q0 + lr) * DM + h*64 + lg*8;
    s16x8 qf0 = *(const s16x8*)(qb);
    s16x8 qf1 = *(const s16x8*)(qb + 32);

    const size_t mrow = (size_t)b * S * S + (size_t)(q0 + lr) * S;

    // staging: thread (w,lane) covers rows w*16+j*8+(lane>>3), 16B each.
    // physical pcol=(lane&7)*16 holds logical col pcol ^ ((row&7)<<4); row&7=lane>>3.
    const int srow_lo = (lane >> 3);                       // row&7
    const int s_le    = (((lane & 7) ^ srow_lo) << 3);     // logical col, elements
#define STAGE(bufi, cc) do {                                                        \
    const int c_ = (cc);                                                            \
    _Pragma("unroll")                                                               \
    for (int j = 0; j < 2; ++j) {                                                   \
        const int row_ = w*16 + j*8 + srow_lo;                                      \
        gload16(Kp + (size_t)(b*S + c_*64 + row_) * 1024 + h*64 + s_le,             \
                &kvbuf[bufi][0][(w*2 + j) * 512]);                                  \
        gload16(Vt + ((size_t)g*64 + row_) * 1024 + c_*64 + s_le,                   \
                &kvbuf[bufi][1][(w*2 + j) * 512]);                                  \
    }                                                                               \
} while (0)

    auto loadm = [&](int c_) -> int4 {
        const size_t off = mrow + c_*64 + w*16 + lg*4;
        if (mask_bytes) {
            uchar4 mb = *(const uchar4*)((const uint8_t*)maskp + off);
            return make_int4(mb.x, mb.y, mb.z, mb.w);
        }
        return *(const int4*)((const int*)maskp + off);
    };

    STAGE(0, 0);
    int4 mk = loadm(0);
    __syncthreads();   // barrier drains vmcnt -> chunk 0 ready

    s16x4 paf[16];
    f32x4 pacc[4] = {};
    float hs = 0.f;
    int cur = 0;
    const int swz = (lr & 7) << 4;   // read-side XOR (row&7 == lr&7 for all reads)

    for (int c = 0; c < 16; ++c) {
        if (c + 1 < 16) STAGE((c + 1) & 1, c + 1);
        int4 mnext;
        if (c + 1 < 16) mnext = loadm(c + 1);

        // QK^T from swizzled LDS K: A-frag row = w*16+lr, kf0 d<32, kf1 d>=32
        const char* kbase = (const char*)&kvbuf[cur][0][0] + (w*16 + lr) * 128;
        s16x8 kf0 = *(const s16x8*)(kbase + ((lg*16) ^ swz));
        s16x8 kf1 = *(const s16x8*)(kbase + ((64 + lg*16) ^ swz));
        f32x4 cc = {};
        cc = __builtin_amdgcn_mfma_f32_16x16x32_bf16(kf0, qf0, cc, 0, 0, 0);
        cc = __builtin_amdgcn_mfma_f32_16x16x32_bf16(kf1, qf1, cc, 0, 0, 0);

        cc[0] = __expf(mk.x ? NEGINF : cc[0] * 0.125f);
        cc[1] = __expf(mk.y ? NEGINF : cc[1] * 0.125f);
        cc[2] = __expf(mk.z ? NEGINF : cc[2] * 0.125f);
        cc[3] = __expf(mk.w ? NEGINF : cc[3] * 0.125f);
        hs += cc[0] + cc[1] + cc[2] + cc[3];
        s16x4 pa;
        pa[0] = (short)f2bf(cc[0]); pa[1] = (short)f2bf(cc[1]);
        pa[2] = (short)f2bf(cc[2]); pa[3] = (short)f2bf(cc[3]);
        paf[c] = pa;

        // PV from swizzled LDS V: B-frag col d=d0*16+lr, k = w*16+lg*4+i
        const char* vb0 = (const char*)&kvbuf[cur][1][0];
#pragma unroll
        for (int d0 = 0; d0 < 4; ++d0) {
            s16x4 vf = *(const s16x4*)(vb0 + (d0*16 + lr) * 128 + ((w*32 + lg*8) ^ swz));
            pacc[d0] = __builtin_amdgcn_mfma_f32_16x16x16bf16_1k(pa, vf, pacc[d0], 0, 0, 0);
        }

        __syncthreads();   // drains vmcnt (next chunk staged) + read-before-restage
        cur ^= 1;
        mk = mnext;
    }
#undef STAGE

    // row sums
    hs += __shfl_xor(hs, 16, 64);
    hs += __shfl_xor(hs, 32, 64);
    if (lane < 16) redB[w][lr] = hs;
    __syncthreads();

    const float tot = redB[0][lr] + redB[1][lr] + redB[2][lr] + redB[3][lr];
    const float inv  = tot > 0.f ? 1.0f / tot : 0.f;
    const float fill = tot > 0.f ? 0.f : (1.0f / 1024.0f);
    float invr[4];
#pragma unroll
    for (int r = 0; r < 4; ++r) {
        const int row = lg*4 + r;
        const float tr = redB[0][row] + redB[1][row] + redB[2][row] + redB[3][row];
        invr[r] = tr > 0.f ? 1.0f / tr : 0.f;
    }

    // attn write (q = q0+lr, col = c*64 + w*16 + lg*4)
    float* arow = attn + (size_t)(b*H + h) * S * S + (size_t)(q0 + lr) * S + w*16 + lg*4;
#pragma unroll
    for (int c = 0; c < 16; ++c) {
        float4 st;
        st.x = fmaf(bf2f((u16)paf[c][0]), inv, fill);
        st.y = fmaf(bf2f((u16)paf[c][1]), inv, fill);
        st.z = fmaf(bf2f((u16)paf[c][2]), inv, fill);
        st.w = fmaf(bf2f((u16)paf[c][3]), inv, fill);
        *(float4*)(arow + c*64) = st;
    }

    // ctx cross-wave reduce in LDS aliased over the dead staging buffer
    float* ctxp = (float*)&kvbuf[0][0][0];   // [4][16][68] floats = 17408 B < 32 KB
#pragma unroll
    for (int d0 = 0; d0 < 4; ++d0)
#pragma unroll
        for (int r = 0; r < 4; ++r)
            ctxp[(w*16 + lg*4 + r) * 68 + d0*16 + lr] = pacc[d0][r] * invr[r];
    __syncthreads();

    {
        const int q  = t >> 4;          // 0..15
        const int d4 = (t & 15) * 4;    // 0..60
        float4 s0 = *(const float4*)&ctxp[(0*16 + q) * 68 + d4];
        float4 s1 = *(const float4*)&ctxp[(1*16 + q) * 68 + d4];
        float4 s2 = *(const float4*)&ctxp[(2*16 + q) * 68 + d4];
        float4 s3 = *(const float4*)&ctxp[(3*16 + q) * 68 + d4];
        float4 sm;
        sm.x = s0.x + s1.x + s2.x + s3.x;
        sm.y = s0.y + s1.y + s2.y + s3.y;
        sm.z = s0.z + s1.z + s2.z + s3.z;
        sm.w = s0.w + s1.w + s2.w + s3.w;
        ushort4 o;
        o.x = f2bf(sm.x); o.y = f2bf(sm.y); o.z = f2bf(sm.z); o.w = f2bf(sm.w);
        *(ushort4*)(ctx + (size_t)(b*S + q0 + q) * DM + h*64 + d4) = o;
    }
}

// ---------------- LayerNorm over rows of 1024 ----------------
__global__ __launch_bounds__(256)
void layernorm(const float* __restrict__ x, const float* __restrict__ gamma,
               const float* __restrict__ beta, float* __restrict__ out)
{
    const int row = blockIdx.x;
    const int t = threadIdx.x;
    const float* xr = x + (size_t)row * DM;
    float4 v = *(const float4*)(xr + t*4);
    float s  = v.x + v.y + v.z + v.w;
    float s2 = v.x*v.x + v.y*v.y + v.z*v.z + v.w*v.w;
#pragma unroll
    for (int d = 1; d < 64; d <<= 1) {
        s  += __shfl_xor(s,  d, 64);
        s2 += __shfl_xor(s2, d, 64);
    }
    __shared__ float ls[4], ls2[4];
    if ((t & 63) == 0) { ls[t >> 6] = s; ls2[t >> 6] = s2; }
    __syncthreads();
    s  = ls[0] + ls[1] + ls[2] + ls[3];
    s2 = ls2[0] + ls2[1] + ls2[2] + ls2[3];
    const float mu  = s * (1.0f / DM);
    const float var = s2 * (1.0f / DM) - mu * mu;
    const float rs  = rsqrtf(var + 1e-5f);
    float4 g  = *(const float4*)(gamma + t*4);
    float4 bb = *(const float4*)(beta  + t*4);
    float4 o;
    o.x = (v.x - mu) * rs * g.x + bb.x;
    o.y = (v.y - mu) * rs * g.y + bb.y;
    o.z = (v.z - mu) * rs * g.z + bb.z;
    o.w = (v.w - mu) * rs * g.w + bb.w;
    *(float4*)(out + (size_t)row * DM + t*4) = o;
}

extern "C" void kernel_launch(void* const* d_in, const int* in_sizes, int n_in,
                              void* d_out, int out_size, void* d_ws, size_t ws_size,
                              hipStream_t stream) {
    const float* Qin  = (const float*)d_in[0];
    const float* Kin  = (const float*)d_in[1];
    const float* Vin  = (const float*)d_in[2];
    const void*  mask = d_in[3];
    const float* Wq   = (const float*)d_in[4];
    const float* Wk   = (const float*)d_in[5];
    const float* Wv   = (const float*)d_in[6];
    const float* Wfc  = (const float*)d_in[7];
    const float* gam  = (const float*)d_in[8];
    const float* bet  = (const float*)d_in[9];

    float* out  = (float*)d_out;
    float* attn = (float*)d_out + (size_t)M * DM;

    char* ws = (char*)d_ws;
    constexpr size_t SZ_X = (size_t)M * DM * 2;    // 16 MiB
    constexpr size_t SZ_W = (size_t)DM * DM * 2;   // 2 MiB
    u16* Xq  = (u16*)(ws);
    u16* Xk  = (u16*)(ws + SZ_X);
    u16* Xv  = (u16*)(ws + 2*SZ_X);
    u16* WqT = (u16*)(ws + 3*SZ_X);
    u16* WkT = (u16*)(ws + 3*SZ_X + SZ_W);
    u16* WvT = (u16*)(ws + 3*SZ_X + 2*SZ_W);
    u16* WfT = (u16*)(ws + 3*SZ_X + 3*SZ_W);
    u16* Qp  = (u16*)(ws + 3*SZ_X + 4*SZ_W);
    u16* Kp  = (u16*)(ws + 4*SZ_X + 4*SZ_W);
    u16* Vt  = (u16*)(ws + 5*SZ_X + 4*SZ_W);
    // aliases onto dead buffers:
    float* preLN = (float*)(ws);               // 32 MiB over Xq+Xk (dead after projections)
    u16*   Ctx   = (u16*)(ws + 2*SZ_X);        // 16 MiB over Xv   (dead after V projection)

    dim3 blk(256);
    cvt_all<<<dim3(M * DM / 1024, 3), blk, 0, stream>>>(Qin, Kin, Vin, Xq, Xk, Xv);
    transpose_all<<<dim3(32, 32, 4), blk, 0, stream>>>(Wq, Wk, Wv, Wfc, WqT, WkT, WvT, WfT);

    gemm_bt<0><<<dim3(64, 8), blk, 0, stream>>>(Xq, WqT, Qp, nullptr);
    gemm_bt<0><<<dim3(64, 8), blk, 0, stream>>>(Xk, WkT, Kp, nullptr);
    gemm_bt<1><<<dim3(64, 8), blk, 0, stream>>>(Xv, WvT, Vt, nullptr);

    attn_fused<<<dim3(8192), blk, 0, stream>>>(Qp, Kp, mask, Vt, attn, Ctx);

    gemm_bt<2><<<dim3(64, 8), blk, 0, stream>>>(Ctx, WfT, preLN, Qin);
    layernorm<<<dim3(M), blk, 0, stream>>>(preLN, gam, bet, out);
}

// Round 10
// 536.357 us; speedup vs baseline: 1.8734x; 1.8734x over previous
//
#include <hip/hip_runtime.h>
#include <stdint.h>

typedef unsigned short u16;
typedef float f32x4 __attribute__((ext_vector_type(4)));
typedef short s16x8 __attribute__((ext_vector_type(8)));
typedef short s16x4 __attribute__((ext_vector_type(4)));

constexpr int B  = 8;
constexpr int S  = 1024;
constexpr int DM = 1024;
constexpr int H  = 16;
constexpr int M  = B * S;          // 8192 rows
constexpr float NEGINF = -1e9f;

__device__ __forceinline__ u16 f2bf(float f) {
    union { float f; uint32_t u; } v; v.f = f;
    uint32_t u = v.u;
    uint32_t r = 0x7FFFu + ((u >> 16) & 1u);   // round-to-nearest-even
    return (u16)((u + r) >> 16);
}
__device__ __forceinline__ float bf2f(u16 h) {
    union { uint32_t u; float f; } v; v.u = ((uint32_t)h) << 16; return v.f;
}

// async global->LDS 16B (m97 form): LDS dest = wave-uniform base + lane*16
__device__ __forceinline__ void gload16(const u16* g, u16* l) {
    __builtin_amdgcn_global_load_lds(
        (const __attribute__((address_space(1))) unsigned int*)g,
        (__attribute__((address_space(3))) unsigned int*)l, 16, 0, 0);
}

// ---------------- fp32 -> bf16, all three inputs in one launch ----------------
__global__ void cvt_all(const float* __restrict__ q, const float* __restrict__ k,
                        const float* __restrict__ v,
                        u16* __restrict__ xq, u16* __restrict__ xk, u16* __restrict__ xv) {
    const float* in; u16* out;
    if (blockIdx.y == 0)      { in = q; out = xq; }
    else if (blockIdx.y == 1) { in = k; out = xk; }
    else                      { in = v; out = xv; }
    int i = (blockIdx.x * 256 + threadIdx.x) * 4;
    float4 val = *(const float4*)(in + i);
    ushort4 o;
    o.x = f2bf(val.x); o.y = f2bf(val.y); o.z = f2bf(val.z); o.w = f2bf(val.w);
    *(ushort4*)(out + i) = o;
}

// ---------------- W[k][n] fp32 -> Wt[n][k] bf16, all four weights ----------------
__global__ void transpose_all(const float* __restrict__ w0, const float* __restrict__ w1,
                              const float* __restrict__ w2, const float* __restrict__ w3,
                              u16* __restrict__ o0, u16* __restrict__ o1,
                              u16* __restrict__ o2, u16* __restrict__ o3) {
    const float* W; u16* Wt;
    switch (blockIdx.z) {
        case 0:  W = w0; Wt = o0; break;
        case 1:  W = w1; Wt = o1; break;
        case 2:  W = w2; Wt = o2; break;
        default: W = w3; Wt = o3; break;
    }
    __shared__ float tile[32][33];
    int n0 = blockIdx.x * 32, k0 = blockIdx.y * 32;
    int tx = threadIdx.x & 31, ty = threadIdx.x >> 5;   // 32 x 8
#pragma unroll
    for (int r = 0; r < 4; ++r)
        tile[ty + r*8][tx] = W[(size_t)(k0 + ty + r*8) * DM + n0 + tx];
    __syncthreads();
#pragma unroll
    for (int r = 0; r < 4; ++r)
        Wt[(size_t)(n0 + ty + r*8) * DM + k0 + tx] = f2bf(tile[tx][ty + r*8]);
}

// ---------------- GEMM: C[M x 1024] = A[M x 1024] * Bt[1024 x 1024]^T ----------------
// m97 structure: 128x128 tile, BK=32, global_load_lds width=16, linear LDS.
// Grid (m,n) = (x,y): same-m blocks share the A-band and the same id%8 -> same XCD.
// EPI 0: C bf16 row-major.  EPI 1: V transposed -> Vt[(b*16+h)*64+d][s].  EPI 2: fp32 + resid.
template<int EPI>
__global__ __launch_bounds__(256, 2)
void gemm_bt(const u16* __restrict__ A, const u16* __restrict__ Bt,
             void* __restrict__ Cv, const float* __restrict__ resid)
{
    __shared__ u16 As[128 * 32];
    __shared__ u16 Bs[128 * 32];
    const int m0 = blockIdx.x * 128;
    const int n0 = blockIdx.y * 128;
    const int t = threadIdx.x;
    const int lane = t & 63;
    const int wid = t >> 6;
    const int wm = (wid >> 1) * 64;
    const int wn = (wid & 1) * 64;
    const int lr = lane & 15;
    const int lg = lane >> 4;

    const u16* Ag = A  + (size_t)(m0 + (t >> 2)) * 1024 + (t & 3) * 8;
    const u16* Bg = Bt + (size_t)(n0 + (t >> 2)) * 1024 + (t & 3) * 8;
    u16* Al = As + t * 8;
    u16* Bl = Bs + t * 8;

    f32x4 acc[4][4] = {};

    for (int kt = 0; kt < 32; ++kt) {
        const int ko = kt * 32;
        __syncthreads();
        gload16(Ag + ko,            Al);
        gload16(Ag + 64*1024 + ko,  Al + 64*32);
        gload16(Bg + ko,            Bl);
        gload16(Bg + 64*1024 + ko,  Bl + 64*32);
        __syncthreads();
        s16x8 af[4], bfr[4];
#pragma unroll
        for (int m = 0; m < 4; ++m)
            af[m] = *(const s16x8*)(As + (wm + m*16 + lr) * 32 + lg * 8);
#pragma unroll
        for (int n = 0; n < 4; ++n)
            bfr[n] = *(const s16x8*)(Bs + (wn + n*16 + lr) * 32 + lg * 8);
#pragma unroll
        for (int m = 0; m < 4; ++m)
#pragma unroll
            for (int n = 0; n < 4; ++n)
                acc[m][n] = __builtin_amdgcn_mfma_f32_16x16x32_bf16(af[m], bfr[n], acc[m][n], 0, 0, 0);
    }

#pragma unroll
    for (int m = 0; m < 4; ++m) {
#pragma unroll
        for (int n = 0; n < 4; ++n) {
            const int rg0 = m0 + wm + m*16 + lg*4;   // D row = (lane>>4)*4 + reg
            const int cg  = n0 + wn + n*16 + lr;     // D col = lane&15
            if constexpr (EPI == 0) {
                u16* C = (u16*)Cv;
#pragma unroll
                for (int r = 0; r < 4; ++r)
                    C[(size_t)(rg0 + r) * 1024 + cg] = f2bf(acc[m][n][r]);
            } else if constexpr (EPI == 1) {
                u16* C = (u16*)Cv;
                const int bb = rg0 >> 10;
                const int s0 = rg0 & 1023;
                const int hh = cg >> 6;
                const int dd = cg & 63;
                ushort4 pk;
                pk.x = f2bf(acc[m][n][0]); pk.y = f2bf(acc[m][n][1]);
                pk.z = f2bf(acc[m][n][2]); pk.w = f2bf(acc[m][n][3]);
                *(ushort4*)(C + (size_t)((bb*16 + hh)*64 + dd) * 1024 + s0) = pk;
            } else {
                float* C = (float*)Cv;
#pragma unroll
                for (int r = 0; r < 4; ++r) {
                    size_t idx = (size_t)(rg0 + r) * 1024 + cg;
                    C[idx] = acc[m][n][r] + resid[idx];
                }
            }
        }
    }
}

// ---------------- fused scores + softmax + attn-write + PV (P via LDS, R3 shape) ----------------
// Grid: 8192 1-D, XCD-swizzled (i bits [12:9]=gHi, [8:3]=qt, [2:0]=gLo; g=b*16+h).
// Block = 16 q-rows, 4 waves.
// QK phase: wave w owns k-slice [w*256, +256). Swapped QK^T (A=K,B=Q):
//   lane holds q=lr, k=w*256+nk*16+lg*4+r, bf16 raw-exp in paf[16] (32 VGPR).
// P exchange: raw-exp P -> Plds[16][1032] (b64 writes ~4-way = b64 floor;
//   b128 reads stride 516 dw == 4 mod 32 -> 2-way, m92-endorsed). ONE barrier.
// PV phase: wave w owns d-slice [w*16, +16), full k: 32x {Plds b128, V s16x8
//   contiguous-16B global} -> mfma_16x16x32 into a single f32x4. No cross-wave
//   reduce (d-slices disjoint). ctx stores 32B-coalesced. invr[r] scales rows
//   q=lg*4+r at the end (raw-exp PV is linear in P).
__global__ __launch_bounds__(256, 2)
void attn_fused(const u16* __restrict__ Qp, const u16* __restrict__ Kp,
                const void* __restrict__ maskp, const u16* __restrict__ Vt,
                float* __restrict__ attn, u16* __restrict__ ctx)
{
    const int i  = blockIdx.x;
    const int qt = (i >> 3) & 63;
    const int g  = ((i >> 9) << 3) | (i & 7);   // g%8 == i%8 -> same XCD per (b,h)
    const int h  = g & 15;
    const int b  = g >> 4;
    const int q0 = qt * 16;

    const int t = threadIdx.x;
    const int lane = t & 63;
    const int w = t >> 6;
    const int lr = lane & 15;
    const int lg = lane >> 4;

    constexpr int PLD = 1032;          // 516 dwords == 4 mod 32
    __shared__ u16 Plds[16][PLD];      // 33 KB
    __shared__ float redB[4][16];

    // mask dtype detect
    uint32_t orv = 0;
    const uint32_t* mw = (const uint32_t*)maskp;
#pragma unroll
    for (int ii = 0; ii < 64; ++ii) orv |= mw[ii];
    const bool mask_bytes = (orv > 1u);

    // Q as B-operand: q = q0+lr, k-elem = d = lg*8+i (+32)
    const u16* qb = Qp + (size_t)(b*S + q0 + lr) * DM + h*64 + lg*8;
    s16x8 qf0 = *(const s16x8*)(qb);
    s16x8 qf1 = *(const s16x8*)(qb + 32);

    const size_t mrow = (size_t)b * S * S + (size_t)(q0 + lr) * S;

    // ---- QK^T + mask + exp -> bf16 paf; also stash into Plds ----
    s16x4 paf[16];
    float hs = 0.f;
#pragma unroll
    for (int nk = 0; nk < 16; ++nk) {
        const u16* kb = Kp + (size_t)(b*S + w*256 + nk*16 + lr) * DM + h*64 + lg*8;
        s16x8 kf0 = *(const s16x8*)(kb);
        s16x8 kf1 = *(const s16x8*)(kb + 32);
        int m0, m1, m2, m3;
        {
            const size_t off = mrow + w*256 + nk*16 + lg*4;
            if (mask_bytes) {
                uchar4 mb = *(const uchar4*)((const uint8_t*)maskp + off);
                m0 = mb.x; m1 = mb.y; m2 = mb.z; m3 = mb.w;
            } else {
                int4 mi = *(const int4*)((const int*)maskp + off);
                m0 = mi.x; m1 = mi.y; m2 = mi.z; m3 = mi.w;
            }
        }
        f32x4 cc = {};
        cc = __builtin_amdgcn_mfma_f32_16x16x32_bf16(kf0, qf0, cc, 0, 0, 0);
        cc = __builtin_amdgcn_mfma_f32_16x16x32_bf16(kf1, qf1, cc, 0, 0, 0);
        cc[0] = __expf(m0 ? NEGINF : cc[0] * 0.125f);
        cc[1] = __expf(m1 ? NEGINF : cc[1] * 0.125f);
        cc[2] = __expf(m2 ? NEGINF : cc[2] * 0.125f);
        cc[3] = __expf(m3 ? NEGINF : cc[3] * 0.125f);
        hs += cc[0] + cc[1] + cc[2] + cc[3];
        s16x4 pa;
        pa[0] = (short)f2bf(cc[0]); pa[1] = (short)f2bf(cc[1]);
        pa[2] = (short)f2bf(cc[2]); pa[3] = (short)f2bf(cc[3]);
        paf[nk] = pa;
        *(s16x4*)&Plds[lr][w*256 + nk*16 + lg*4] = pa;   // raw-exp P, 8B write
    }

    // row sums (q = lr)
    hs += __shfl_xor(hs, 16, 64);
    hs += __shfl_xor(hs, 32, 64);
    if (lane < 16) redB[w][lr] = hs;
    __syncthreads();   // covers Plds writes AND redB

    const float tot = redB[0][lr] + redB[1][lr] + redB[2][lr] + redB[3][lr];
    const float inv  = tot > 0.f ? 1.0f / tot : 0.f;
    const float fill = tot > 0.f ? 0.f : (1.0f / 1024.0f);
    float invr[4];
#pragma unroll
    for (int r = 0; r < 4; ++r) {
        const int row = lg*4 + r;
        const float tr = redB[0][row] + redB[1][row] + redB[2][row] + redB[3][row];
        invr[r] = tr > 0.f ? 1.0f / tr : 0.f;
    }

    // attn write (q = q0+lr, k = w*256 + nk*16 + lg*4): float4 stores from paf
    float* arow = attn + (size_t)(b*H + h) * S * S + (size_t)(q0 + lr) * S + w*256 + lg*4;
#pragma unroll
    for (int nk = 0; nk < 16; ++nk) {
        float4 st;
        st.x = fmaf(bf2f((u16)paf[nk][0]), inv, fill);
        st.y = fmaf(bf2f((u16)paf[nk][1]), inv, fill);
        st.z = fmaf(bf2f((u16)paf[nk][2]), inv, fill);
        st.w = fmaf(bf2f((u16)paf[nk][3]), inv, fill);
        *(float4*)(arow + nk*16) = st;
    }

    // ---- PV: wave w owns d-slice [w*16, +16), full k ----
    // A = Plds[q=lr][k=kt*32+lg*8..+8] (b128, 2-way); B = Vt row (d) contiguous 16B.
    const u16* vrow = Vt + ((size_t)g*64 + w*16 + lr) * S;
    f32x4 pacc = {};
#pragma unroll
    for (int kt = 0; kt < 32; ++kt) {
        s16x8 af = *(const s16x8*)&Plds[lr][kt*32 + lg*8];
        s16x8 vf = *(const s16x8*)(vrow + kt*32 + lg*8);
        pacc = __builtin_amdgcn_mfma_f32_16x16x32_bf16(af, vf, pacc, 0, 0, 0);
    }
    // D[col=lr -> d = w*16+lr][row=lg*4+r -> q]; scale by invr[r]; 2B stores,
    // 16 lanes consecutive d -> 32B segments, 4 q-rows per wave.
#pragma unroll
    for (int r = 0; r < 4; ++r)
        ctx[(size_t)(b*S + q0 + lg*4 + r) * DM + h*64 + w*16 + lr] = f2bf(pacc[r] * invr[r]);
}

// ---------------- LayerNorm over rows of 1024 ----------------
__global__ __launch_bounds__(256)
void layernorm(const float* __restrict__ x, const float* __restrict__ gamma,
               const float* __restrict__ beta, float* __restrict__ out)
{
    const int row = blockIdx.x;
    const int t = threadIdx.x;
    const float* xr = x + (size_t)row * DM;
    float4 v = *(const float4*)(xr + t*4);
    float s  = v.x + v.y + v.z + v.w;
    float s2 = v.x*v.x + v.y*v.y + v.z*v.z + v.w*v.w;
#pragma unroll
    for (int d = 1; d < 64; d <<= 1) {
        s  += __shfl_xor(s,  d, 64);
        s2 += __shfl_xor(s2, d, 64);
    }
    __shared__ float ls[4], ls2[4];
    if ((t & 63) == 0) { ls[t >> 6] = s; ls2[t >> 6] = s2; }
    __syncthreads();
    s  = ls[0] + ls[1] + ls[2] + ls[3];
    s2 = ls2[0] + ls2[1] + ls2[2] + ls2[3];
    const float mu  = s * (1.0f / DM);
    const float var = s2 * (1.0f / DM) - mu * mu;
    const float rs  = rsqrtf(var + 1e-5f);
    float4 g  = *(const float4*)(gamma + t*4);
    float4 bb = *(const float4*)(beta  + t*4);
    float4 o;
    o.x = (v.x - mu) * rs * g.x + bb.x;
    o.y = (v.y - mu) * rs * g.y + bb.y;
    o.z = (v.z - mu) * rs * g.z + bb.z;
    o.w = (v.w - mu) * rs * g.w + bb.w;
    *(float4*)(out + (size_t)row * DM + t*4) = o;
}

extern "C" void kernel_launch(void* const* d_in, const int* in_sizes, int n_in,
                              void* d_out, int out_size, void* d_ws, size_t ws_size,
                              hipStream_t stream) {
    const float* Qin  = (const float*)d_in[0];
    const float* Kin  = (const float*)d_in[1];
    const float* Vin  = (const float*)d_in[2];
    const void*  mask = d_in[3];
    const float* Wq   = (const float*)d_in[4];
    const float* Wk   = (const float*)d_in[5];
    const float* Wv   = (const float*)d_in[6];
    const float* Wfc  = (const float*)d_in[7];
    const float* gam  = (const float*)d_in[8];
    const float* bet  = (const float*)d_in[9];

    float* out  = (float*)d_out;
    float* attn = (float*)d_out + (size_t)M * DM;

    char* ws = (char*)d_ws;
    constexpr size_t SZ_X = (size_t)M * DM * 2;    // 16 MiB
    constexpr size_t SZ_W = (size_t)DM * DM * 2;   // 2 MiB
    u16* Xq  = (u16*)(ws);
    u16* Xk  = (u16*)(ws + SZ_X);
    u16* Xv  = (u16*)(ws + 2*SZ_X);
    u16* WqT = (u16*)(ws + 3*SZ_X);
    u16* WkT = (u16*)(ws + 3*SZ_X + SZ_W);
    u16* WvT = (u16*)(ws + 3*SZ_X + 2*SZ_W);
    u16* WfT = (u16*)(ws + 3*SZ_X + 3*SZ_W);
    u16* Qp  = (u16*)(ws + 3*SZ_X + 4*SZ_W);
    u16* Kp  = (u16*)(ws + 4*SZ_X + 4*SZ_W);
    u16* Vt  = (u16*)(ws + 5*SZ_X + 4*SZ_W);
    // aliases onto dead buffers:
    float* preLN = (float*)(ws);               // 32 MiB over Xq+Xk (dead after projections)
    u16*   Ctx   = (u16*)(ws + 2*SZ_X);        // 16 MiB over Xv   (dead after V projection)

    dim3 blk(256);
    cvt_all<<<dim3(M * DM / 1024, 3), blk, 0, stream>>>(Qin, Kin, Vin, Xq, Xk, Xv);
    transpose_all<<<dim3(32, 32, 4), blk, 0, stream>>>(Wq, Wk, Wv, Wfc, WqT, WkT, WvT, WfT);

    gemm_bt<0><<<dim3(64, 8), blk, 0, stream>>>(Xq, WqT, Qp, nullptr);
    gemm_bt<0><<<dim3(64, 8), blk, 0, stream>>>(Xk, WkT, Kp, nullptr);
    gemm_bt<1><<<dim3(64, 8), blk, 0, stream>>>(Xv, WvT, Vt, nullptr);

    attn_fused<<<dim3(8192), blk, 0, stream>>>(Qp, Kp, mask, Vt, attn, Ctx);

    gemm_bt<2><<<dim3(64, 8), blk, 0, stream>>>(Ctx, WfT, preLN, Qin);
    layernorm<<<dim3(M), blk, 0, stream>>>(preLN, gam, bet, out);
}

// Round 12
// 509.502 us; speedup vs baseline: 1.9721x; 1.0527x over previous
//
#include <hip/hip_runtime.h>
#include <stdint.h>

typedef unsigned short u16;
typedef float f32x4 __attribute__((ext_vector_type(4)));
typedef short s16x8 __attribute__((ext_vector_type(8)));
typedef short s16x4 __attribute__((ext_vector_type(4)));

constexpr int B  = 8;
constexpr int S  = 1024;
constexpr int DM = 1024;
constexpr int H  = 16;
constexpr int M  = B * S;          // 8192 rows
constexpr float NEGINF = -1e9f;

__device__ __forceinline__ u16 f2bf(float f) {
    union { float f; uint32_t u; } v; v.f = f;
    uint32_t u = v.u;
    uint32_t r = 0x7FFFu + ((u >> 16) & 1u);   // round-to-nearest-even
    return (u16)((u + r) >> 16);
}
__device__ __forceinline__ float bf2f(u16 h) {
    union { uint32_t u; float f; } v; v.u = ((uint32_t)h) << 16; return v.f;
}

// async global->LDS 16B (m97 form): LDS dest = wave-uniform base + lane*16
__device__ __forceinline__ void gload16(const u16* g, u16* l) {
    __builtin_amdgcn_global_load_lds(
        (const __attribute__((address_space(1))) unsigned int*)g,
        (__attribute__((address_space(3))) unsigned int*)l, 16, 0, 0);
}

// ---------------- fp32 -> bf16, all three inputs in one launch ----------------
__global__ void cvt_all(const float* __restrict__ q, const float* __restrict__ k,
                        const float* __restrict__ v,
                        u16* __restrict__ xq, u16* __restrict__ xk, u16* __restrict__ xv) {
    const float* in; u16* out;
    if (blockIdx.y == 0)      { in = q; out = xq; }
    else if (blockIdx.y == 1) { in = k; out = xk; }
    else                      { in = v; out = xv; }
    int i = (blockIdx.x * 256 + threadIdx.x) * 4;
    float4 val = *(const float4*)(in + i);
    ushort4 o;
    o.x = f2bf(val.x); o.y = f2bf(val.y); o.z = f2bf(val.z); o.w = f2bf(val.w);
    *(ushort4*)(out + i) = o;
}

// ---------------- W[k][n] fp32 -> Wt[n][k] bf16, all four weights ----------------
__global__ void transpose_all(const float* __restrict__ w0, const float* __restrict__ w1,
                              const float* __restrict__ w2, const float* __restrict__ w3,
                              u16* __restrict__ o0, u16* __restrict__ o1,
                              u16* __restrict__ o2, u16* __restrict__ o3) {
    const float* W; u16* Wt;
    switch (blockIdx.z) {
        case 0:  W = w0; Wt = o0; break;
        case 1:  W = w1; Wt = o1; break;
        case 2:  W = w2; Wt = o2; break;
        default: W = w3; Wt = o3; break;
    }
    __shared__ float tile[32][33];
    int n0 = blockIdx.x * 32, k0 = blockIdx.y * 32;
    int tx = threadIdx.x & 31, ty = threadIdx.x >> 5;   // 32 x 8
#pragma unroll
    for (int r = 0; r < 4; ++r)
        tile[ty + r*8][tx] = W[(size_t)(k0 + ty + r*8) * DM + n0 + tx];
    __syncthreads();
#pragma unroll
    for (int r = 0; r < 4; ++r)
        Wt[(size_t)(n0 + ty + r*8) * DM + k0 + tx] = f2bf(tile[tx][ty + r*8]);
}

// ---------------- GEMM: C[M x 1024] = A[M x 1024] * Bt[1024 x 1024]^T ----------------
// m97 structure: 128x128 tile, BK=32, global_load_lds width=16, linear LDS.
// Grid (m,n) = (x,y): same-m blocks share the A-band and the same id%8 -> same XCD.
// EPI 0: C bf16 row-major.  EPI 1: V transposed -> Vt[(b*16+h)*64+d][s].  EPI 2: fp32 + resid.
template<int EPI>
__global__ __launch_bounds__(256, 2)
void gemm_bt(const u16* __restrict__ A, const u16* __restrict__ Bt,
             void* __restrict__ Cv, const float* __restrict__ resid)
{
    __shared__ u16 As[128 * 32];
    __shared__ u16 Bs[128 * 32];
    const int m0 = blockIdx.x * 128;
    const int n0 = blockIdx.y * 128;
    const int t = threadIdx.x;
    const int lane = t & 63;
    const int wid = t >> 6;
    const int wm = (wid >> 1) * 64;
    const int wn = (wid & 1) * 64;
    const int lr = lane & 15;
    const int lg = lane >> 4;

    const u16* Ag = A  + (size_t)(m0 + (t >> 2)) * 1024 + (t & 3) * 8;
    const u16* Bg = Bt + (size_t)(n0 + (t >> 2)) * 1024 + (t & 3) * 8;
    u16* Al = As + t * 8;
    u16* Bl = Bs + t * 8;

    f32x4 acc[4][4] = {};

    for (int kt = 0; kt < 32; ++kt) {
        const int ko = kt * 32;
        __syncthreads();
        gload16(Ag + ko,            Al);
        gload16(Ag + 64*1024 + ko,  Al + 64*32);
        gload16(Bg + ko,            Bl);
        gload16(Bg + 64*1024 + ko,  Bl + 64*32);
        __syncthreads();
        s16x8 af[4], bfr[4];
#pragma unroll
        for (int m = 0; m < 4; ++m)
            af[m] = *(const s16x8*)(As + (wm + m*16 + lr) * 32 + lg * 8);
#pragma unroll
        for (int n = 0; n < 4; ++n)
            bfr[n] = *(const s16x8*)(Bs + (wn + n*16 + lr) * 32 + lg * 8);
#pragma unroll
        for (int m = 0; m < 4; ++m)
#pragma unroll
            for (int n = 0; n < 4; ++n)
                acc[m][n] = __builtin_amdgcn_mfma_f32_16x16x32_bf16(af[m], bfr[n], acc[m][n], 0, 0, 0);
    }

#pragma unroll
    for (int m = 0; m < 4; ++m) {
#pragma unroll
        for (int n = 0; n < 4; ++n) {
            const int rg0 = m0 + wm + m*16 + lg*4;   // D row = (lane>>4)*4 + reg
            const int cg  = n0 + wn + n*16 + lr;     // D col = lane&15
            if constexpr (EPI == 0) {
                u16* C = (u16*)Cv;
#pragma unroll
                for (int r = 0; r < 4; ++r)
                    C[(size_t)(rg0 + r) * 1024 + cg] = f2bf(acc[m][n][r]);
            } else if constexpr (EPI == 1) {
                u16* C = (u16*)Cv;
                const int bb = rg0 >> 10;
                const int s0 = rg0 & 1023;
                const int hh = cg >> 6;
                const int dd = cg & 63;
                ushort4 pk;
                pk.x = f2bf(acc[m][n][0]); pk.y = f2bf(acc[m][n][1]);
                pk.z = f2bf(acc[m][n][2]); pk.w = f2bf(acc[m][n][3]);
                *(ushort4*)(C + (size_t)((bb*16 + hh)*64 + dd) * 1024 + s0) = pk;
            } else {
                float* C = (float*)Cv;
#pragma unroll
                for (int r = 0; r < 4; ++r) {
                    size_t idx = (size_t)(rg0 + r) * 1024 + cg;
                    C[idx] = acc[m][n][r] + resid[idx];
                }
            }
        }
    }
}

// ---------------- fused scores + softmax + PV + attn-write (stores LAST) ----------------
// Grid: 8192 1-D, XCD-swizzled (i bits [12:9]=gHi, [8:3]=qt, [2:0]=gLo; g=b*16+h).
// Identical to R10 except phase order: after the barrier, PV (loads+MFMA) runs
// FIRST and the 537MB attn store stream is issued LAST as nontemporal stores
// (via ext_vector f32x4 — __builtin_nontemporal_store rejects HIP float4 struct).
// Rationale: vmcnt counts loads AND stores in FIFO order -> any load-use wait
// issued after the attn stores transitively waits for the store stream to
// retire (HBM-rate drain). With stores last, nothing waits on them.
__global__ __launch_bounds__(256, 2)
void attn_fused(const u16* __restrict__ Qp, const u16* __restrict__ Kp,
                const void* __restrict__ maskp, const u16* __restrict__ Vt,
                float* __restrict__ attn, u16* __restrict__ ctx)
{
    const int i  = blockIdx.x;
    const int qt = (i >> 3) & 63;
    const int g  = ((i >> 9) << 3) | (i & 7);   // g%8 == i%8 -> same XCD per (b,h)
    const int h  = g & 15;
    const int b  = g >> 4;
    const int q0 = qt * 16;

    const int t = threadIdx.x;
    const int lane = t & 63;
    const int w = t >> 6;
    const int lr = lane & 15;
    const int lg = lane >> 4;

    constexpr int PLD = 1032;          // 516 dwords == 4 mod 32
    __shared__ u16 Plds[16][PLD];      // 33 KB
    __shared__ float redB[4][16];

    // mask dtype detect
    uint32_t orv = 0;
    const uint32_t* mw = (const uint32_t*)maskp;
#pragma unroll
    for (int ii = 0; ii < 64; ++ii) orv |= mw[ii];
    const bool mask_bytes = (orv > 1u);

    // Q as B-operand: q = q0+lr, k-elem = d = lg*8+i (+32)
    const u16* qb = Qp + (size_t)(b*S + q0 + lr) * DM + h*64 + lg*8;
    s16x8 qf0 = *(const s16x8*)(qb);
    s16x8 qf1 = *(const s16x8*)(qb + 32);

    const size_t mrow = (size_t)b * S * S + (size_t)(q0 + lr) * S;

    // ---- QK^T + mask + exp -> bf16 paf; also stash into Plds ----
    s16x4 paf[16];
    float hs = 0.f;
#pragma unroll
    for (int nk = 0; nk < 16; ++nk) {
        const u16* kb = Kp + (size_t)(b*S + w*256 + nk*16 + lr) * DM + h*64 + lg*8;
        s16x8 kf0 = *(const s16x8*)(kb);
        s16x8 kf1 = *(const s16x8*)(kb + 32);
        int m0, m1, m2, m3;
        {
            const size_t off = mrow + w*256 + nk*16 + lg*4;
            if (mask_bytes) {
                uchar4 mb = *(const uchar4*)((const uint8_t*)maskp + off);
                m0 = mb.x; m1 = mb.y; m2 = mb.z; m3 = mb.w;
            } else {
                int4 mi = *(const int4*)((const int*)maskp + off);
                m0 = mi.x; m1 = mi.y; m2 = mi.z; m3 = mi.w;
            }
        }
        f32x4 cc = {};
        cc = __builtin_amdgcn_mfma_f32_16x16x32_bf16(kf0, qf0, cc, 0, 0, 0);
        cc = __builtin_amdgcn_mfma_f32_16x16x32_bf16(kf1, qf1, cc, 0, 0, 0);
        cc[0] = __expf(m0 ? NEGINF : cc[0] * 0.125f);
        cc[1] = __expf(m1 ? NEGINF : cc[1] * 0.125f);
        cc[2] = __expf(m2 ? NEGINF : cc[2] * 0.125f);
        cc[3] = __expf(m3 ? NEGINF : cc[3] * 0.125f);
        hs += cc[0] + cc[1] + cc[2] + cc[3];
        s16x4 pa;
        pa[0] = (short)f2bf(cc[0]); pa[1] = (short)f2bf(cc[1]);
        pa[2] = (short)f2bf(cc[2]); pa[3] = (short)f2bf(cc[3]);
        paf[nk] = pa;
        *(s16x4*)&Plds[lr][w*256 + nk*16 + lg*4] = pa;   // raw-exp P, 8B write
    }

    // row sums (q = lr)
    hs += __shfl_xor(hs, 16, 64);
    hs += __shfl_xor(hs, 32, 64);
    if (lane < 16) redB[w][lr] = hs;
    __syncthreads();   // covers Plds writes AND redB

    const float tot = redB[0][lr] + redB[1][lr] + redB[2][lr] + redB[3][lr];
    const float inv  = tot > 0.f ? 1.0f / tot : 0.f;
    const float fill = tot > 0.f ? 0.f : (1.0f / 1024.0f);
    float invr[4];
#pragma unroll
    for (int r = 0; r < 4; ++r) {
        const int row = lg*4 + r;
        const float tr = redB[0][row] + redB[1][row] + redB[2][row] + redB[3][row];
        invr[r] = tr > 0.f ? 1.0f / tr : 0.f;
    }

    // ---- PV FIRST: wave w owns d-slice [w*16, +16), full k ----
    // A = Plds[q=lr][k=kt*32+lg*8..+8] (b128, 2-way); B = Vt row (d) contiguous 16B.
    const u16* vrow = Vt + ((size_t)g*64 + w*16 + lr) * S;
    f32x4 pacc = {};
#pragma unroll
    for (int kt = 0; kt < 32; ++kt) {
        s16x8 af = *(const s16x8*)&Plds[lr][kt*32 + lg*8];
        s16x8 vf = *(const s16x8*)(vrow + kt*32 + lg*8);
        pacc = __builtin_amdgcn_mfma_f32_16x16x32_bf16(af, vf, pacc, 0, 0, 0);
    }
    // D[col=lr -> d = w*16+lr][row=lg*4+r -> q]; scale by invr[r].
#pragma unroll
    for (int r = 0; r < 4; ++r)
        ctx[(size_t)(b*S + q0 + lg*4 + r) * DM + h*64 + w*16 + lr] = f2bf(pacc[r] * invr[r]);

    // ---- attn stores LAST (nontemporal, ext_vector f32x4) ----
    float* arow = attn + (size_t)(b*H + h) * S * S + (size_t)(q0 + lr) * S + w*256 + lg*4;
#pragma unroll
    for (int nk = 0; nk < 16; ++nk) {
        f32x4 st;
        st[0] = fmaf(bf2f((u16)paf[nk][0]), inv, fill);
        st[1] = fmaf(bf2f((u16)paf[nk][1]), inv, fill);
        st[2] = fmaf(bf2f((u16)paf[nk][2]), inv, fill);
        st[3] = fmaf(bf2f((u16)paf[nk][3]), inv, fill);
        __builtin_nontemporal_store(st, (f32x4*)(arow + nk*16));
    }
}

// ---------------- LayerNorm over rows of 1024 ----------------
__global__ __launch_bounds__(256)
void layernorm(const float* __restrict__ x, const float* __restrict__ gamma,
               const float* __restrict__ beta, float* __restrict__ out)
{
    const int row = blockIdx.x;
    const int t = threadIdx.x;
    const float* xr = x + (size_t)row * DM;
    float4 v = *(const float4*)(xr + t*4);
    float s  = v.x + v.y + v.z + v.w;
    float s2 = v.x*v.x + v.y*v.y + v.z*v.z + v.w*v.w;
#pragma unroll
    for (int d = 1; d < 64; d <<= 1) {
        s  += __shfl_xor(s,  d, 64);
        s2 += __shfl_xor(s2, d, 64);
    }
    __shared__ float ls[4], ls2[4];
    if ((t & 63) == 0) { ls[t >> 6] = s; ls2[t >> 6] = s2; }
    __syncthreads();
    s  = ls[0] + ls[1] + ls[2] + ls[3];
    s2 = ls2[0] + ls2[1] + ls2[2] + ls2[3];
    const float mu  = s * (1.0f / DM);
    const float var = s2 * (1.0f / DM) - mu * mu;
    const float rs  = rsqrtf(var + 1e-5f);
    float4 g  = *(const float4*)(gamma + t*4);
    float4 bb = *(const float4*)(beta  + t*4);
    float4 o;
    o.x = (v.x - mu) * rs * g.x + bb.x;
    o.y = (v.y - mu) * rs * g.y + bb.y;
    o.z = (v.z - mu) * rs * g.z + bb.z;
    o.w = (v.w - mu) * rs * g.w + bb.w;
    *(float4*)(out + (size_t)row * DM + t*4) = o;
}

extern "C" void kernel_launch(void* const* d_in, const int* in_sizes, int n_in,
                              void* d_out, int out_size, void* d_ws, size_t ws_size,
                              hipStream_t stream) {
    const float* Qin  = (const float*)d_in[0];
    const float* Kin  = (const float*)d_in[1];
    const float* Vin  = (const float*)d_in[2];
    const void*  mask = d_in[3];
    const float* Wq   = (const float*)d_in[4];
    const float* Wk   = (const float*)d_in[5];
    const float* Wv   = (const float*)d_in[6];
    const float* Wfc  = (const float*)d_in[7];
    const float* gam  = (const float*)d_in[8];
    const float* bet  = (const float*)d_in[9];

    float* out  = (float*)d_out;
    float* attn = (float*)d_out + (size_t)M * DM;

    char* ws = (char*)d_ws;
    constexpr size_t SZ_X = (size_t)M * DM * 2;    // 16 MiB
    constexpr size_t SZ_W = (size_t)DM * DM * 2;   // 2 MiB
    u16* Xq  = (u16*)(ws);
    u16* Xk  = (u16*)(ws + SZ_X);
    u16* Xv  = (u16*)(ws + 2*SZ_X);
    u16* WqT = (u16*)(ws + 3*SZ_X);
    u16* WkT = (u16*)(ws + 3*SZ_X + SZ_W);
    u16* WvT = (u16*)(ws + 3*SZ_X + 2*SZ_W);
    u16* WfT = (u16*)(ws + 3*SZ_X + 3*SZ_W);
    u16* Qp  = (u16*)(ws + 3*SZ_X + 4*SZ_W);
    u16* Kp  = (u16*)(ws + 4*SZ_X + 4*SZ_W);
    u16* Vt  = (u16*)(ws + 5*SZ_X + 4*SZ_W);
    // aliases onto dead buffers:
    float* preLN = (float*)(ws);               // 32 MiB over Xq+Xk (dead after projections)
    u16*   Ctx   = (u16*)(ws + 2*SZ_X);        // 16 MiB over Xv   (dead after V projection)

    dim3 blk(256);
    cvt_all<<<dim3(M * DM / 1024, 3), blk, 0, stream>>>(Qin, Kin, Vin, Xq, Xk, Xv);
    transpose_all<<<dim3(32, 32, 4), blk, 0, stream>>>(Wq, Wk, Wv, Wfc, WqT, WkT, WvT, WfT);

    gemm_bt<0><<<dim3(64, 8), blk, 0, stream>>>(Xq, WqT, Qp, nullptr);
    gemm_bt<0><<<dim3(64, 8), blk, 0, stream>>>(Xk, WkT, Kp, nullptr);
    gemm_bt<1><<<dim3(64, 8), blk, 0, stream>>>(Xv, WvT, Vt, nullptr);

    attn_fused<<<dim3(8192), blk, 0, stream>>>(Qp, Kp, mask, Vt, attn, Ctx);

    gemm_bt<2><<<dim3(64, 8), blk, 0, stream>>>(Ctx, WfT, preLN, Qin);
    layernorm<<<dim3(M), blk, 0, stream>>>(preLN, gam, bet, out);
}